// Round 9
// baseline (619.182 us; speedup 1.0000x reference)
//
#include <hip/hip_runtime.h>
#include <hip/hip_bf16.h>

#define N_A 100000
#define N_G 25000
#define DD 128
#define E_B 400000
#define E_O 100000
#define E_R 200000
#define E_P 200000
#define EALL 900000
#define NSLOT 250000
#define STRIDE 64

static constexpr float BN_INV_C = 0.99999500003749969f; // 1/sqrt(1+1e-5)

typedef __attribute__((ext_vector_type(8))) short bf16x8;
typedef __attribute__((ext_vector_type(4))) float f32x4;

__device__ __forceinline__ unsigned short f2bf(float f) {
    unsigned u = __float_as_uint(f);
    unsigned r = (u + 0x7FFFu + ((u >> 16) & 1u)) >> 16;
    return (unsigned short)r;
}
__device__ __forceinline__ float bf2f(unsigned short s) {
    return __uint_as_float(((unsigned)s) << 16);
}
__device__ __forceinline__ float lrelu(float v) { return v > 0.f ? v : 0.2f * v; }

// ---------------- fused input cast ----------------
__global__ void k_xcast_all(const float* __restrict__ xa, const float* __restrict__ xg,
                            unsigned short* __restrict__ xab, unsigned short* __restrict__ xgb) {
    int t = blockIdx.x * blockDim.x + threadIdx.x;
    if (t < N_A * 32) {
        float4 v = *(const float4*)(xa + (size_t)t * 4);
        ushort4 o; o.x = f2bf(v.x); o.y = f2bf(v.y); o.z = f2bf(v.z); o.w = f2bf(v.w);
        *(ushort4*)(xab + (size_t)t * 4) = o;
    } else {
        int t2 = t - N_A * 32;
        if (t2 >= N_G * 32) return;
        float4 v = *(const float4*)(xg + (size_t)t2 * 4);
        ushort4 o; o.x = f2bf(v.x); o.y = f2bf(v.y); o.z = f2bf(v.z); o.w = f2bf(v.w);
        *(ushort4*)(xgb + (size_t)t2 * 4) = o;
    }
}

// ---------------- fused weight cast/transpose ----------------
struct WcSeg { const float* src; unsigned short* dst; int K; int N; int ldk; int off; };
struct WcArgs { WcSeg s[10]; };

__global__ void k_wcast_all(WcArgs a) {
    WcSeg sg = a.s[blockIdx.y];
    int t = blockIdx.x * blockDim.x + threadIdx.x;
    if (t >= sg.K * sg.N) return;
    int n = t % sg.N, k = t / sg.N;
    sg.dst[(size_t)n * sg.ldk + sg.off + k] = f2bf(sg.src[t]);
}

// ---------------- attention weight-vector precompute ----------------
// wv[0]=refine-l (groups), wv[1]=refine-r (atoms), wv[2]=pool-l (atoms), wv[3]=pool-r (groups)
__global__ void k_war_all(const float* __restrict__ rWfc, const float* __restrict__ ral,
                          const float* __restrict__ rar, const float* __restrict__ pWfc,
                          const float* __restrict__ pal, const float* __restrict__ par,
                          float* __restrict__ wv) {
    int bsel = blockIdx.x;
    const float* W = bsel < 2 ? rWfc : pWfc;
    const float* vec = bsel == 0 ? ral : bsel == 1 ? rar : bsel == 2 ? pal : par;
    float* o = wv + bsel * 512;
    int t = threadIdx.x;
    int k = t >> 2, h = t & 3;
    const float* wr = W + (size_t)k * 512 + h * 128;
    const float* av = vec + h * 128;
    float s = 0.f;
    for (int d = 0; d < 128; ++d) s += wr[d] * av[d];
    o[t] = s;
}

// ---------------- bucketed adjacency build (4 graphs) ----------------
__global__ void k_adj_fill(const int* __restrict__ bs, const int* __restrict__ bd,
                           const int* __restrict__ os, const int* __restrict__ od,
                           const int* __restrict__ rs, const int* __restrict__ rd,
                           const int* __restrict__ ps, const int* __restrict__ pd,
                           int* __restrict__ deg, uint2* __restrict__ adj,
                           int* __restrict__ heads, int* __restrict__ nxt) {
    int t = blockIdx.x * blockDim.x + threadIdx.x;
    int e, base, go; const int* S; const int* D;
    if (t < E_B) { e = t; S = bs; D = bd; base = 0; go = 0; }
    else if (t < E_B + E_O) { e = t - E_B; S = os; D = od; base = 100000; go = E_B; }
    else if (t < E_B + E_O + E_R) { e = t - (E_B + E_O); S = rs; D = rd; base = 125000; go = E_B + E_O; }
    else if (t < EALL) { e = t - (E_B + E_O + E_R); S = ps; D = pd; base = 225000; go = E_B + E_O + E_R; }
    else return;
    int d = D[e], s = S[e];
    int ns = base + d;
    int pos = atomicAdd(&deg[ns], 1);
    if (pos < STRIDE) adj[(size_t)ns * STRIDE + pos] = make_uint2((unsigned)e, (unsigned)s);
    else nxt[go + e] = atomicExch(&heads[ns], e);
}

// ---------------- GINE gather (wave per node, 4 nodes/block) ----------------
__global__ __launch_bounds__(256) void k_gine_gather_all(
    const unsigned short* __restrict__ xAb, const unsigned short* __restrict__ xGb,
    const float* __restrict__ efB, const float* __restrict__ efO,
    const int* __restrict__ bsrc, const int* __restrict__ osrc,
    const int* __restrict__ deg, const uint2* __restrict__ adj,
    const int* __restrict__ heads, const int* __restrict__ nxt,
    const float* __restrict__ beps, const float* __restrict__ oeps,
    unsigned short* __restrict__ h0A, unsigned short* __restrict__ h0G) {
    int wid = threadIdx.x >> 6, lane = threadIdx.x & 63;
    int n = blockIdx.x * 4 + wid;
    __shared__ uint2 gl[4][STRIDE];
    const unsigned short* xs; const unsigned short* xdrow; const float* ef;
    const int* esrc; const int* nx; float ep; unsigned short* outp; int nn, base, go;
    if (n < N_A) {
        nn = n; xs = xAb; xdrow = xAb + (size_t)n * DD; ef = efB; esrc = bsrc;
        base = 0; go = 0; ep = 1.0f + beps[0]; outp = h0A + (size_t)n * DD;
    } else {
        nn = n - N_A; xs = xGb; xdrow = xGb + (size_t)nn * DD; ef = efO; esrc = osrc;
        base = 100000; go = E_B; ep = 1.0f + oeps[0]; outp = h0G + (size_t)nn * DD;
    }
    nx = nxt + go;
    int d = deg[base + nn];
    int cb = min(d, STRIDE);
    if (lane < cb) gl[wid][lane] = adj[(size_t)(base + nn) * STRIDE + lane];
    __syncthreads();
    float2 acc = make_float2(0.f, 0.f);
    for (int i = 0; i < cb; ++i) {
        uint2 es = gl[wid][i];
        unsigned xa = *(const unsigned*)(xs + (size_t)es.y * DD + lane * 2);
        float2 ev = *(const float2*)(ef + (size_t)es.x * DD + lane * 2);
        acc.x += fmaxf(bf2f((unsigned short)(xa & 0xffff)) + ev.x, 0.f);
        acc.y += fmaxf(bf2f((unsigned short)(xa >> 16)) + ev.y, 0.f);
    }
    if (d > STRIDE) {
        for (int e = heads[base + nn]; e >= 0; e = nx[e]) {
            int s = esrc[e];
            unsigned xa = *(const unsigned*)(xs + (size_t)s * DD + lane * 2);
            float2 ev = *(const float2*)(ef + (size_t)e * DD + lane * 2);
            acc.x += fmaxf(bf2f((unsigned short)(xa & 0xffff)) + ev.x, 0.f);
            acc.y += fmaxf(bf2f((unsigned short)(xa >> 16)) + ev.y, 0.f);
        }
    }
    unsigned xd = *(const unsigned*)(xdrow + lane * 2);
    float rx = ep * bf2f((unsigned short)(xd & 0xffff)) + acc.x;
    float ry = ep * bf2f((unsigned short)(xd >> 16)) + acc.y;
    *(unsigned*)(outp + lane * 2) = (unsigned)f2bf(rx) | ((unsigned)f2bf(ry) << 16);
}

// ---------------- node logits: both src-side (el) and dst-side (er) per node ----------------
__global__ void k_logit_all(const unsigned short* __restrict__ xAb,
                            const unsigned short* __restrict__ xGb,
                            const float* __restrict__ wv,
                            float* __restrict__ elR, float* __restrict__ elP,
                            float* __restrict__ erR, float* __restrict__ erP) {
    int t = blockIdx.x * blockDim.x + threadIdx.x;
    const unsigned short* xr; const float* wl; const float* wr_; float* ol; float* orr; int idx;
    if (t < N_A * 4) {
        idx = t; xr = xAb + (size_t)(t >> 2) * DD; wl = wv + 1024; wr_ = wv + 512;
        ol = elP; orr = erR;
    } else {
        int t2 = t - N_A * 4;
        if (t2 >= N_G * 4) return;
        idx = t2; xr = xGb + (size_t)(t2 >> 2) * DD; wl = wv; wr_ = wv + 1536;
        ol = elR; orr = erP;
    }
    int h = idx & 3;
    float sl = 0.f, sr = 0.f;
#pragma unroll
    for (int k = 0; k < DD; k += 8) {
        uint4 w = *(const uint4*)(xr + k);
        unsigned wa[4] = {w.x, w.y, w.z, w.w};
#pragma unroll
        for (int q = 0; q < 4; ++q) {
            float x0 = bf2f((unsigned short)(wa[q] & 0xffff));
            float x1 = bf2f((unsigned short)(wa[q] >> 16));
            int k0 = (k + q * 2) * 4 + h, k1 = (k + q * 2 + 1) * 4 + h;
            sl += x0 * wl[k0] + x1 * wl[k1];
            sr += x0 * wr_[k0] + x1 * wr_[k1];
        }
    }
    ol[idx] = sl;
    orr[idx] = sr;
}

// ---------------- edge-parallel exp + denominator (no max: logits bounded) ----------------
__global__ void k_exp_all(const float* __restrict__ elR, const float* __restrict__ erR,
                          const float* __restrict__ elP, const float* __restrict__ erP,
                          const int* __restrict__ rs, const int* __restrict__ rd,
                          const int* __restrict__ ps, const int* __restrict__ pd,
                          float* __restrict__ exR, float* __restrict__ exP,
                          float* __restrict__ denR, float* __restrict__ denP) {
    int t = blockIdx.x * blockDim.x + threadIdx.x;
    if (t < E_R * 4) {
        int e = t >> 2, h = t & 3;
        float v = lrelu(elR[rs[e] * 4 + h] + erR[rd[e] * 4 + h]);
        float x = __expf(v);
        exR[t] = x;
        atomicAdd(&denR[rd[e] * 4 + h], x);
    } else {
        int t2 = t - E_R * 4;
        if (t2 >= E_P * 4) return;
        int e = t2 >> 2, h = t2 & 3;
        float v = lrelu(elP[ps[e] * 4 + h] + erP[pd[e] * 4 + h]);
        float x = __expf(v);
        exP[t2] = x;
        atomicAdd(&denP[pd[e] * 4 + h], x);
    }
}

// ---------------- GAT gather: pure weighted aggregation ----------------
__global__ __launch_bounds__(256) void k_att_gather_all(
    const unsigned short* __restrict__ xAb, const unsigned short* __restrict__ xGb,
    const float* __restrict__ exR, const float* __restrict__ exP,
    const float* __restrict__ denR, const float* __restrict__ denP,
    const int* __restrict__ rsrc, const int* __restrict__ psrc,
    const int* __restrict__ deg, const uint2* __restrict__ adj,
    const int* __restrict__ heads, const int* __restrict__ nxt,
    unsigned short* __restrict__ A2r, unsigned short* __restrict__ A2p) {
    int wid = threadIdx.x >> 6, lane = threadIdx.x & 63;
    int n = blockIdx.x * 4 + wid;
    __shared__ uint2 gl[4][STRIDE];
    const unsigned short* xs; const float* ex; const float* den;
    const int* esrc; const int* nx; unsigned short* A2; int nn, base, go;
    if (n < N_A) {
        nn = n; xs = xGb; ex = exR; den = denR; esrc = rsrc;
        base = 125000; go = E_B + E_O; A2 = A2r + (size_t)n * 512;
    } else {
        nn = n - N_A; xs = xAb; ex = exP; den = denP; esrc = psrc;
        base = 225000; go = E_B + E_O + E_R; A2 = A2p + (size_t)nn * 512;
    }
    nx = nxt + go;
    int d = deg[base + nn];
    int cb = min(d, STRIDE);
    if (lane < cb) gl[wid][lane] = adj[(size_t)(base + nn) * STRIDE + lane];
    __syncthreads();
    float4 dv = *(const float4*)(den + (size_t)nn * 4);
    float inv0 = 1.f / fmaxf(dv.x, 1e-9f);
    float inv1 = 1.f / fmaxf(dv.y, 1e-9f);
    float inv2 = 1.f / fmaxf(dv.z, 1e-9f);
    float inv3 = 1.f / fmaxf(dv.w, 1e-9f);
    float acc[4][2] = {};
    for (int i = 0; i < cb; ++i) {
        uint2 es = gl[wid][i];
        float4 e4 = *(const float4*)(ex + (size_t)es.x * 4);
        unsigned xw = *(const unsigned*)(xs + (size_t)es.y * DD + lane * 2);
        float x0 = bf2f((unsigned short)(xw & 0xffff));
        float x1 = bf2f((unsigned short)(xw >> 16));
        float a0 = e4.x * inv0, a1 = e4.y * inv1, a2 = e4.z * inv2, a3 = e4.w * inv3;
        acc[0][0] += a0 * x0; acc[0][1] += a0 * x1;
        acc[1][0] += a1 * x0; acc[1][1] += a1 * x1;
        acc[2][0] += a2 * x0; acc[2][1] += a2 * x1;
        acc[3][0] += a3 * x0; acc[3][1] += a3 * x1;
    }
    if (d > STRIDE) {
        for (int e = heads[base + nn]; e >= 0; e = nx[e]) {
            int s = esrc[e];
            float4 e4 = *(const float4*)(ex + (size_t)e * 4);
            unsigned xw = *(const unsigned*)(xs + (size_t)s * DD + lane * 2);
            float x0 = bf2f((unsigned short)(xw & 0xffff));
            float x1 = bf2f((unsigned short)(xw >> 16));
            float a0 = e4.x * inv0, a1 = e4.y * inv1, a2 = e4.z * inv2, a3 = e4.w * inv3;
            acc[0][0] += a0 * x0; acc[0][1] += a0 * x1;
            acc[1][0] += a1 * x0; acc[1][1] += a1 * x1;
            acc[2][0] += a2 * x0; acc[2][1] += a2 * x1;
            acc[3][0] += a3 * x0; acc[3][1] += a3 * x1;
        }
    }
#pragma unroll
    for (int h = 0; h < 4; ++h) {
        unsigned o = (unsigned)f2bf(acc[h][0]) | ((unsigned)f2bf(acc[h][1]) << 16);
        *(unsigned*)(A2 + h * 128 + lane * 2) = o;
    }
}

// ---------------- fused 2-layer MLP block (GEMM1 -> BN+ReLU -> LDS -> GEMM2) ----------------
// GATK=0: hidden = relu(BN(A@W1 + b1)); out(bf16) = hidden@W2 + b2
// GATK=1: hidden = relu(BN(A2_chunk@Wfc + xd@Wres + b1)); out(f32) = hidden@Wout + b2 + bf2f(addbf)
#define LDK 40
#define LDH 136
template <int GATK>
__device__ __forceinline__ void mlp_block(
    const unsigned short* __restrict__ A, const unsigned short* __restrict__ Axd,
    const unsigned short* __restrict__ W1t, int ldk1,
    const unsigned short* __restrict__ W2t, int ldk2,
    const float* __restrict__ b1, const float* __restrict__ g1, const float* __restrict__ be1,
    const float* __restrict__ b2, const unsigned short* __restrict__ addbf,
    void* __restrict__ Cptr, int row0, int M, int nch,
    unsigned short* As, unsigned short* Bs, unsigned short* Hs) {
    const int tid = threadIdx.x;
    const int wave = tid >> 6, lane = tid & 63;
    const int wr = wave >> 1, wc = wave & 1;
    const int l16 = lane & 15, khalf = (lane >> 4) * 8;
    const int rq = (lane >> 4) * 4;
    const int r_0 = tid >> 2, ko = (tid & 3) * 8;
    const int r_1 = r_0 + 64;
    const int K1 = GATK ? 256 : 128;
    f32x4 oacc[4][4] = {};
    for (int c = 0; c < nch; ++c) {
        f32x4 hacc[4][4] = {};
        for (int k0 = 0; k0 < K1; k0 += 32) {
            __syncthreads();
            int kk = k0 + ko;
            int ra = min(row0 + r_0, M - 1);
            uint4 va;
            if (GATK) va = (kk < 128) ? *(const uint4*)(A + (size_t)ra * 512 + c * 128 + kk)
                                      : *(const uint4*)(Axd + (size_t)ra * 128 + (kk - 128));
            else      va = *(const uint4*)(A + (size_t)ra * 128 + kk);
            *(uint4*)(&As[r_0 * LDK + ko]) = va;
            ra = min(row0 + r_1, M - 1);
            if (GATK) va = (kk < 128) ? *(const uint4*)(A + (size_t)ra * 512 + c * 128 + kk)
                                      : *(const uint4*)(Axd + (size_t)ra * 128 + (kk - 128));
            else      va = *(const uint4*)(A + (size_t)ra * 128 + kk);
            *(uint4*)(&As[r_1 * LDK + ko]) = va;
            uint4 vb = *(const uint4*)(W1t + (size_t)(c * 128 + r_0) * ldk1 + kk);
            *(uint4*)(&Bs[r_0 * LDK + ko]) = vb;
            vb = *(const uint4*)(W1t + (size_t)(c * 128 + r_1) * ldk1 + kk);
            *(uint4*)(&Bs[r_1 * LDK + ko]) = vb;
            __syncthreads();
            bf16x8 af[4], bfr[4];
#pragma unroll
            for (int i = 0; i < 4; ++i)
                af[i] = *(const bf16x8*)(&As[(wr * 64 + i * 16 + l16) * LDK + khalf]);
#pragma unroll
            for (int j = 0; j < 4; ++j)
                bfr[j] = *(const bf16x8*)(&Bs[(wc * 64 + j * 16 + l16) * LDK + khalf]);
#pragma unroll
            for (int i = 0; i < 4; ++i)
#pragma unroll
                for (int j = 0; j < 4; ++j)
                    hacc[i][j] = __builtin_amdgcn_mfma_f32_16x16x32_bf16(af[i], bfr[j], hacc[i][j], 0, 0, 0);
        }
        // hidden epilogue -> Hs (bf16)
        __syncthreads();
#pragma unroll
        for (int i = 0; i < 4; ++i) {
#pragma unroll
            for (int reg = 0; reg < 4; ++reg) {
                int rrow = wr * 64 + i * 16 + rq + reg;
#pragma unroll
                for (int j = 0; j < 4; ++j) {
                    int ccol = wc * 64 + j * 16 + l16;
                    int ch = c * 128 + ccol;
                    float v = hacc[i][j][reg] + b1[ch];
                    v = g1[ch] * (v * BN_INV_C) + be1[ch];
                    Hs[rrow * LDH + ccol] = f2bf(fmaxf(v, 0.f));
                }
            }
        }
        __syncthreads();
        // GEMM2: oacc += Hs @ W2t[:, c*128 + k]
        for (int k0 = 0; k0 < 128; k0 += 32) {
            __syncthreads();
            int kk = c * 128 + k0 + ko;
            uint4 vb = *(const uint4*)(W2t + (size_t)r_0 * ldk2 + kk);
            *(uint4*)(&Bs[r_0 * LDK + ko]) = vb;
            vb = *(const uint4*)(W2t + (size_t)r_1 * ldk2 + kk);
            *(uint4*)(&Bs[r_1 * LDK + ko]) = vb;
            __syncthreads();
            bf16x8 af[4], bfr[4];
#pragma unroll
            for (int i = 0; i < 4; ++i)
                af[i] = *(const bf16x8*)(&Hs[(wr * 64 + i * 16 + l16) * LDH + k0 + khalf]);
#pragma unroll
            for (int j = 0; j < 4; ++j)
                bfr[j] = *(const bf16x8*)(&Bs[(wc * 64 + j * 16 + l16) * LDK + khalf]);
#pragma unroll
            for (int i = 0; i < 4; ++i)
#pragma unroll
                for (int j = 0; j < 4; ++j)
                    oacc[i][j] = __builtin_amdgcn_mfma_f32_16x16x32_bf16(af[i], bfr[j], oacc[i][j], 0, 0, 0);
        }
    }
    // final epilogue
#pragma unroll
    for (int i = 0; i < 4; ++i) {
#pragma unroll
        for (int reg = 0; reg < 4; ++reg) {
            int r = row0 + wr * 64 + i * 16 + rq + reg;
            if (r >= M) continue;
#pragma unroll
            for (int j = 0; j < 4; ++j) {
                int cc = wc * 64 + j * 16 + l16;
                size_t idx = (size_t)r * 128 + cc;
                float v = oacc[i][j][reg] + b2[cc];
                if (GATK) ((float*)Cptr)[idx] = v + bf2f(addbf[idx]);
                else ((unsigned short*)Cptr)[idx] = f2bf(v);
            }
        }
    }
}

#define NBA 782
#define NBG 196

__global__ __launch_bounds__(256) void k_gine_mlp(
    const unsigned short* __restrict__ h0A, const unsigned short* __restrict__ h0G,
    const unsigned short* __restrict__ WtB1, const unsigned short* __restrict__ WtB2,
    const unsigned short* __restrict__ WtO1, const unsigned short* __restrict__ WtO2,
    const float* __restrict__ bb1, const float* __restrict__ bg1, const float* __restrict__ bbe1,
    const float* __restrict__ bb2,
    const float* __restrict__ ob1, const float* __restrict__ og1, const float* __restrict__ obe1,
    const float* __restrict__ ob2,
    unsigned short* __restrict__ G1a, unsigned short* __restrict__ G1g) {
    __shared__ unsigned short As[128 * LDK];
    __shared__ unsigned short Bs[128 * LDK];
    __shared__ unsigned short Hs[128 * LDH];
    int bx = blockIdx.x;
    if (bx < NBA)
        mlp_block<0>(h0A, nullptr, WtB1, 128, WtB2, 256, bb1, bg1, bbe1, bb2, nullptr,
                     G1a, bx * 128, N_A, 2, As, Bs, Hs);
    else
        mlp_block<0>(h0G, nullptr, WtO1, 128, WtO2, 256, ob1, og1, obe1, ob2, nullptr,
                     G1g, (bx - NBA) * 128, N_G, 2, As, Bs, Hs);
}

__global__ __launch_bounds__(256) void k_gat_mlp(
    const unsigned short* __restrict__ A2r, const unsigned short* __restrict__ A2p,
    const unsigned short* __restrict__ xAb, const unsigned short* __restrict__ xGb,
    const unsigned short* __restrict__ WtR, const unsigned short* __restrict__ WtRo,
    const unsigned short* __restrict__ WtP, const unsigned short* __restrict__ WtPo,
    const float* __restrict__ rbias, const float* __restrict__ rg, const float* __restrict__ rb,
    const float* __restrict__ rbout,
    const float* __restrict__ pbias, const float* __restrict__ pg, const float* __restrict__ pb,
    const float* __restrict__ pbout,
    const unsigned short* __restrict__ G1a, const unsigned short* __restrict__ G1g,
    float* __restrict__ out) {
    __shared__ unsigned short As[128 * LDK];
    __shared__ unsigned short Bs[128 * LDK];
    __shared__ unsigned short Hs[128 * LDH];
    int bx = blockIdx.x;
    if (bx < NBA)
        mlp_block<1>(A2r, xAb, WtR, 256, WtRo, 512, rbias, rg, rb, rbout, G1a,
                     out, bx * 128, N_A, 4, As, Bs, Hs);
    else
        mlp_block<1>(A2p, xGb, WtP, 256, WtPo, 512, pbias, pg, pb, pbout, G1g,
                     out + (size_t)N_A * DD, (bx - NBA) * 128, N_G, 4, As, Bs, Hs);
}

extern "C" void kernel_launch(void* const* d_in, const int* in_sizes, int n_in,
                              void* d_out, int out_size, void* d_ws, size_t ws_size,
                              hipStream_t stream) {
    const float* x_atom = (const float*)d_in[0];
    const float* x_group = (const float*)d_in[1];
    const float* ef_bond = (const float*)d_in[2];
    const float* ef_ov = (const float*)d_in[3];
    const int* bond_src = (const int*)d_in[4];
    const int* bond_dst = (const int*)d_in[5];
    const int* ov_src = (const int*)d_in[6];
    const int* ov_dst = (const int*)d_in[7];
    const int* ref_src = (const int*)d_in[8];
    const int* ref_dst = (const int*)d_in[9];
    const int* pool_src = (const int*)d_in[10];
    const int* pool_dst = (const int*)d_in[11];
    const float* b_eps = (const float*)d_in[12];
    const float* b_W1 = (const float*)d_in[13];
    const float* b_b1 = (const float*)d_in[14];
    const float* b_g1 = (const float*)d_in[15];
    const float* b_be1 = (const float*)d_in[16];
    const float* b_W2 = (const float*)d_in[17];
    const float* b_b2 = (const float*)d_in[18];
    const float* o_eps = (const float*)d_in[19];
    const float* o_W1 = (const float*)d_in[20];
    const float* o_b1 = (const float*)d_in[21];
    const float* o_g1 = (const float*)d_in[22];
    const float* o_be1 = (const float*)d_in[23];
    const float* o_W2 = (const float*)d_in[24];
    const float* o_b2 = (const float*)d_in[25];
    const float* r_Wfc = (const float*)d_in[26];
    const float* r_al = (const float*)d_in[27];
    const float* r_ar = (const float*)d_in[28];
    const float* r_Wres = (const float*)d_in[29];
    const float* r_bias = (const float*)d_in[30];
    const float* r_g = (const float*)d_in[31];
    const float* r_b = (const float*)d_in[32];
    const float* r_Wout = (const float*)d_in[33];
    const float* r_bout = (const float*)d_in[34];
    const float* p_Wfc = (const float*)d_in[35];
    const float* p_al = (const float*)d_in[36];
    const float* p_ar = (const float*)d_in[37];
    const float* p_Wres = (const float*)d_in[38];
    const float* p_bias = (const float*)d_in[39];
    const float* p_g = (const float*)d_in[40];
    const float* p_b = (const float*)d_in[41];
    const float* p_Wout = (const float*)d_in[42];
    const float* p_bout = (const float*)d_in[43];

    float* out = (float*)d_out;
    char* wsb = (char*)d_ws;
    unsigned short* xAb = (unsigned short*)(wsb + 0);             // 25.6 MB
    unsigned short* xGb = (unsigned short*)(wsb + 26000000);      // 6.4 MB
    unsigned short* WtB1 = (unsigned short*)(wsb + 33000000);     // weight slots
    unsigned short* WtB2 = WtB1 + 32768;
    unsigned short* WtO1 = WtB2 + 32768;
    unsigned short* WtO2 = WtO1 + 32768;
    unsigned short* WtR  = WtO2 + 32768;   // 512x256 (Wfc|Wres)
    unsigned short* WtRo = WtR + 131072;   // 128x512
    unsigned short* WtP  = WtRo + 65536;   // 512x256
    unsigned short* WtPo = WtP + 131072;   // 128x512
    float* wv   = (float*)(wsb + 34100000);                       // 4x512 f32
    int* heads  = (int*)(wsb + 36300000);                         // 250k int
    int* nxt    = (int*)(wsb + 37400000);                         // 900k int
    unsigned short* h0A = (unsigned short*)(wsb + 41100000);      // 25.6 MB
    unsigned short* h0G = (unsigned short*)(wsb + 66800000);      // 6.4 MB
    unsigned short* G1a = (unsigned short*)(wsb + 124600000);     // 25.6 MB
    unsigned short* G1g = (unsigned short*)(wsb + 150300000);     // 6.4 MB
    unsigned short* A2r = (unsigned short*)(wsb + 156800000);     // 102.4 MB
    unsigned short* A2p = (unsigned short*)(wsb + 259300000);     // 25.6 MB
    uint2* adj  = (uint2*)(wsb + 414000000);                      // 128 MB
    int* deg    = (int*)(wsb + 543000000);                        // 1 MB
    float* F    = (float*)(wsb + 544000000);                      // logit/ex block
    float* elR  = F;               // N_G*4
    float* elP  = F + 100000;      // N_A*4
    float* erR  = F + 500000;      // N_A*4
    float* erP  = F + 900000;      // N_G*4
    float* denR = F + 1000000;     // N_A*4
    float* denP = F + 1400000;     // N_G*4
    float* exR  = F + 1500000;     // E_R*4
    float* exP  = F + 2300000;     // E_P*4

    // 1. input casts
    k_xcast_all<<<((N_A + N_G) * 32 + 255) / 256, 256, 0, stream>>>(x_atom, x_group, xAb, xGb);
    // 2. weight casts
    WcArgs wa;
    wa.s[0] = {b_W1, WtB1, 128, 256, 128, 0};
    wa.s[1] = {b_W2, WtB2, 256, 128, 256, 0};
    wa.s[2] = {o_W1, WtO1, 128, 256, 128, 0};
    wa.s[3] = {o_W2, WtO2, 256, 128, 256, 0};
    wa.s[4] = {r_Wfc, WtR, 128, 512, 256, 0};
    wa.s[5] = {r_Wres, WtR, 128, 512, 256, 128};
    wa.s[6] = {r_Wout, WtRo, 512, 128, 512, 0};
    wa.s[7] = {p_Wfc, WtP, 128, 512, 256, 0};
    wa.s[8] = {p_Wres, WtP, 128, 512, 256, 128};
    wa.s[9] = {p_Wout, WtPo, 512, 128, 512, 0};
    k_wcast_all<<<dim3(256, 10), 256, 0, stream>>>(wa);
    // 3. attention weight vectors
    k_war_all<<<4, 512, 0, stream>>>(r_Wfc, r_al, r_ar, p_Wfc, p_al, p_ar, wv);
    // 4. bucketed adjacency + zeroed denominators
    hipMemsetAsync(deg, 0, NSLOT * 4, stream);
    hipMemsetAsync(heads, 0xFF, NSLOT * 4, stream);
    hipMemsetAsync(denR, 0, 500000 * 4, stream);
    k_adj_fill<<<(EALL + 255) / 256, 256, 0, stream>>>(
        bond_src, bond_dst, ov_src, ov_dst, ref_src, ref_dst, pool_src, pool_dst,
        deg, adj, heads, nxt);
    // 5. GINE gathers
    k_gine_gather_all<<<31250, 256, 0, stream>>>(xAb, xGb, ef_bond, ef_ov, bond_src, ov_src,
                                                 deg, adj, heads, nxt, b_eps, o_eps, h0A, h0G);
    // 6. fused GINE MLPs -> G1
    k_gine_mlp<<<NBA + NBG, 256, 0, stream>>>(h0A, h0G, WtB1, WtB2, WtO1, WtO2,
                                              b_b1, b_g1, b_be1, b_b2, o_b1, o_g1, o_be1, o_b2,
                                              G1a, G1g);
    // 7. node logits (el + er fused)
    k_logit_all<<<((N_A + N_G) * 4 + 255) / 256, 256, 0, stream>>>(xAb, xGb, wv, elR, elP, erR, erP);
    // 8. edge-parallel exp + denominators
    k_exp_all<<<((E_R + E_P) * 4 + 255) / 256, 256, 0, stream>>>(elR, erR, elP, erP,
        ref_src, ref_dst, pool_src, pool_dst, exR, exP, denR, denP);
    // 9. GAT aggregation (pure gather)
    k_att_gather_all<<<31250, 256, 0, stream>>>(xAb, xGb, exR, exP, denR, denP, ref_src, pool_src,
                                                deg, adj, heads, nxt, A2r, A2p);
    // 10. fused GAT MLPs -> out (single f32 write, + GINE partial)
    k_gat_mlp<<<NBA + NBG, 256, 0, stream>>>(A2r, A2p, xAb, xGb, WtR, WtRo, WtP, WtPo,
                                             r_bias, r_g, r_b, r_bout, p_bias, p_g, p_b, p_bout,
                                             G1a, G1g, out);
}

// Round 10
// 542.263 us; speedup vs baseline: 1.1418x; 1.1418x over previous
//
#include <hip/hip_runtime.h>
#include <hip/hip_bf16.h>

#define N_A 100000
#define N_G 25000
#define DD 128
#define E_B 400000
#define E_O 100000
#define E_R 200000
#define E_P 200000
#define EALL 900000
#define NSLOT 250000
#define STRIDE 64

static constexpr float BN_INV_C = 0.99999500003749969f; // 1/sqrt(1+1e-5)

typedef __attribute__((ext_vector_type(8))) short bf16x8;
typedef __attribute__((ext_vector_type(4))) float f32x4;

__device__ __forceinline__ unsigned short f2bf(float f) {
    unsigned u = __float_as_uint(f);
    unsigned r = (u + 0x7FFFu + ((u >> 16) & 1u)) >> 16;
    return (unsigned short)r;
}
__device__ __forceinline__ float bf2f(unsigned short s) {
    return __uint_as_float(((unsigned)s) << 16);
}
__device__ __forceinline__ float lrelu(float v) { return v > 0.f ? v : 0.2f * v; }

// ---------------- prep: xcast + wcast + war + adj_fill in one launch ----------------
struct WcSeg { const float* src; unsigned short* dst; int K; int N; int ldk; int off; };
struct PrepArgs {
    const float* xa; const float* xg;
    unsigned short* xab; unsigned short* xgb;
    WcSeg wc[10];
    const float* rWfc; const float* ral; const float* rar;
    const float* pWfc; const float* pal; const float* par;
    float* wv;
    const int* bs; const int* bd; const int* os; const int* od;
    const int* rs; const int* rd; const int* ps; const int* pd;
    int* deg; uint2* adj; int* heads; int* nxt;
};

#define PB_XC 15625
#define PB_WC 2560
#define PB_WAR 8

__global__ __launch_bounds__(256) void k_prep(PrepArgs p) {
    int bx = blockIdx.x, tid = threadIdx.x;
    if (bx < PB_XC) {
        int t = bx * 256 + tid;
        if (t < N_A * 32) {
            float4 v = *(const float4*)(p.xa + (size_t)t * 4);
            ushort4 o; o.x = f2bf(v.x); o.y = f2bf(v.y); o.z = f2bf(v.z); o.w = f2bf(v.w);
            *(ushort4*)(p.xab + (size_t)t * 4) = o;
        } else {
            int t2 = t - N_A * 32;
            if (t2 < N_G * 32) {
                float4 v = *(const float4*)(p.xg + (size_t)t2 * 4);
                ushort4 o; o.x = f2bf(v.x); o.y = f2bf(v.y); o.z = f2bf(v.z); o.w = f2bf(v.w);
                *(ushort4*)(p.xgb + (size_t)t2 * 4) = o;
            }
        }
    } else if (bx < PB_XC + PB_WC) {
        int b2 = bx - PB_XC;
        WcSeg sg = p.wc[b2 >> 8];
        int t = ((b2 & 255) << 8) + tid;
        if (t < sg.K * sg.N) {
            int n = t % sg.N, k = t / sg.N;
            sg.dst[(size_t)n * sg.ldk + sg.off + k] = f2bf(sg.src[t]);
        }
    } else if (bx < PB_XC + PB_WC + PB_WAR) {
        int b3 = bx - (PB_XC + PB_WC);
        int bsel = b3 >> 1;
        int t = ((b3 & 1) << 8) + tid;   // 512 threads per bsel
        const float* W = bsel < 2 ? p.rWfc : p.pWfc;
        const float* vec = bsel == 0 ? p.ral : bsel == 1 ? p.rar : bsel == 2 ? p.pal : p.par;
        int k = t >> 2, h = t & 3;
        const float* wr = W + (size_t)k * 512 + h * 128;
        const float* av = vec + h * 128;
        float s = 0.f;
        for (int d = 0; d < 128; ++d) s += wr[d] * av[d];
        p.wv[bsel * 512 + t] = s;
    } else {
        int t = (bx - (PB_XC + PB_WC + PB_WAR)) * 256 + tid;
        int e, base, go; const int* S; const int* D;
        if (t < E_B) { e = t; S = p.bs; D = p.bd; base = 0; go = 0; }
        else if (t < E_B + E_O) { e = t - E_B; S = p.os; D = p.od; base = 100000; go = E_B; }
        else if (t < E_B + E_O + E_R) { e = t - (E_B + E_O); S = p.rs; D = p.rd; base = 125000; go = E_B + E_O; }
        else if (t < EALL) { e = t - (E_B + E_O + E_R); S = p.ps; D = p.pd; base = 225000; go = E_B + E_O + E_R; }
        else return;
        int d = D[e], s = S[e];
        int ns = base + d;
        int pos = atomicAdd(&p.deg[ns], 1);
        if (pos < STRIDE) p.adj[(size_t)ns * STRIDE + pos] = make_uint2((unsigned)e, (unsigned)s);
        else p.nxt[go + e] = atomicExch(&p.heads[ns], e);
    }
}

// ---------------- GINE gather (wave/node) + node logits, one launch ----------------
__global__ __launch_bounds__(256) void k_gather_logit(
    const unsigned short* __restrict__ xAb, const unsigned short* __restrict__ xGb,
    const float* __restrict__ efB, const float* __restrict__ efO,
    const int* __restrict__ bsrc, const int* __restrict__ osrc,
    const int* __restrict__ deg, const uint2* __restrict__ adj,
    const int* __restrict__ heads, const int* __restrict__ nxt,
    const float* __restrict__ beps, const float* __restrict__ oeps,
    unsigned short* __restrict__ h0A, unsigned short* __restrict__ h0G,
    const float* __restrict__ wv,
    float* __restrict__ elR, float* __restrict__ elP,
    float* __restrict__ erR, float* __restrict__ erP) {
    __shared__ uint2 gl[4][STRIDE];
    int bx = blockIdx.x;
    if (bx < 31250) {
        int wid = threadIdx.x >> 6, lane = threadIdx.x & 63;
        int n = bx * 4 + wid;
        const unsigned short* xs; const unsigned short* xdrow; const float* ef;
        const int* esrc; const int* nx; float ep; unsigned short* outp; int nn, base, go;
        if (n < N_A) {
            nn = n; xs = xAb; xdrow = xAb + (size_t)n * DD; ef = efB; esrc = bsrc;
            base = 0; go = 0; ep = 1.0f + beps[0]; outp = h0A + (size_t)n * DD;
        } else {
            nn = n - N_A; xs = xGb; xdrow = xGb + (size_t)nn * DD; ef = efO; esrc = osrc;
            base = 100000; go = E_B; ep = 1.0f + oeps[0]; outp = h0G + (size_t)nn * DD;
        }
        nx = nxt + go;
        int d = deg[base + nn];
        int cb = min(d, STRIDE);
        if (lane < cb) gl[wid][lane] = adj[(size_t)(base + nn) * STRIDE + lane];
        __syncthreads();
        float2 acc = make_float2(0.f, 0.f);
        for (int i = 0; i < cb; ++i) {
            uint2 es = gl[wid][i];
            unsigned xa = *(const unsigned*)(xs + (size_t)es.y * DD + lane * 2);
            float2 ev = *(const float2*)(ef + (size_t)es.x * DD + lane * 2);
            acc.x += fmaxf(bf2f((unsigned short)(xa & 0xffff)) + ev.x, 0.f);
            acc.y += fmaxf(bf2f((unsigned short)(xa >> 16)) + ev.y, 0.f);
        }
        if (d > STRIDE) {
            for (int e = heads[base + nn]; e >= 0; e = nx[e]) {
                int s = esrc[e];
                unsigned xa = *(const unsigned*)(xs + (size_t)s * DD + lane * 2);
                float2 ev = *(const float2*)(ef + (size_t)e * DD + lane * 2);
                acc.x += fmaxf(bf2f((unsigned short)(xa & 0xffff)) + ev.x, 0.f);
                acc.y += fmaxf(bf2f((unsigned short)(xa >> 16)) + ev.y, 0.f);
            }
        }
        unsigned xd = *(const unsigned*)(xdrow + lane * 2);
        float rx = ep * bf2f((unsigned short)(xd & 0xffff)) + acc.x;
        float ry = ep * bf2f((unsigned short)(xd >> 16)) + acc.y;
        *(unsigned*)(outp + lane * 2) = (unsigned)f2bf(rx) | ((unsigned)f2bf(ry) << 16);
    } else {
        int t = (bx - 31250) * 256 + threadIdx.x;
        const unsigned short* xr; const float* wl; const float* wr_; float* ol; float* orr; int idx;
        if (t < N_A * 4) {
            idx = t; xr = xAb + (size_t)(t >> 2) * DD; wl = wv + 1024; wr_ = wv + 512;
            ol = elP; orr = erR;
        } else {
            int t2 = t - N_A * 4;
            if (t2 >= N_G * 4) return;
            idx = t2; xr = xGb + (size_t)(t2 >> 2) * DD; wl = wv; wr_ = wv + 1536;
            ol = elR; orr = erP;
        }
        int h = idx & 3;
        float sl = 0.f, sr = 0.f;
#pragma unroll
        for (int k = 0; k < DD; k += 8) {
            uint4 w = *(const uint4*)(xr + k);
            unsigned wa[4] = {w.x, w.y, w.z, w.w};
#pragma unroll
            for (int q = 0; q < 4; ++q) {
                float x0 = bf2f((unsigned short)(wa[q] & 0xffff));
                float x1 = bf2f((unsigned short)(wa[q] >> 16));
                int k0 = (k + q * 2) * 4 + h, k1 = (k + q * 2 + 1) * 4 + h;
                sl += x0 * wl[k0] + x1 * wl[k1];
                sr += x0 * wr_[k0] + x1 * wr_[k1];
            }
        }
        ol[idx] = sl;
        orr[idx] = sr;
    }
}

// ---------------- edge-parallel exp + denominator ----------------
__global__ void k_exp_all(const float* __restrict__ elR, const float* __restrict__ erR,
                          const float* __restrict__ elP, const float* __restrict__ erP,
                          const int* __restrict__ rs, const int* __restrict__ rd,
                          const int* __restrict__ ps, const int* __restrict__ pd,
                          float* __restrict__ exR, float* __restrict__ exP,
                          float* __restrict__ denR, float* __restrict__ denP) {
    int t = blockIdx.x * blockDim.x + threadIdx.x;
    if (t < E_R * 4) {
        int e = t >> 2, h = t & 3;
        float v = lrelu(elR[rs[e] * 4 + h] + erR[rd[e] * 4 + h]);
        float x = __expf(v);
        exR[t] = x;
        atomicAdd(&denR[rd[e] * 4 + h], x);
    } else {
        int t2 = t - E_R * 4;
        if (t2 >= E_P * 4) return;
        int e = t2 >> 2, h = t2 & 3;
        float v = lrelu(elP[ps[e] * 4 + h] + erP[pd[e] * 4 + h]);
        float x = __expf(v);
        exP[t2] = x;
        atomicAdd(&denP[pd[e] * 4 + h], x);
    }
}

// ---------------- GAT gather: pure weighted aggregation ----------------
__global__ __launch_bounds__(256) void k_att_gather_all(
    const unsigned short* __restrict__ xAb, const unsigned short* __restrict__ xGb,
    const float* __restrict__ exR, const float* __restrict__ exP,
    const float* __restrict__ denR, const float* __restrict__ denP,
    const int* __restrict__ rsrc, const int* __restrict__ psrc,
    const int* __restrict__ deg, const uint2* __restrict__ adj,
    const int* __restrict__ heads, const int* __restrict__ nxt,
    unsigned short* __restrict__ A2r, unsigned short* __restrict__ A2p) {
    int wid = threadIdx.x >> 6, lane = threadIdx.x & 63;
    int n = blockIdx.x * 4 + wid;
    __shared__ uint2 gl[4][STRIDE];
    const unsigned short* xs; const float* ex; const float* den;
    const int* esrc; const int* nx; unsigned short* A2; int nn, base, go;
    if (n < N_A) {
        nn = n; xs = xGb; ex = exR; den = denR; esrc = rsrc;
        base = 125000; go = E_B + E_O; A2 = A2r + (size_t)n * 512;
    } else {
        nn = n - N_A; xs = xAb; ex = exP; den = denP; esrc = psrc;
        base = 225000; go = E_B + E_O + E_R; A2 = A2p + (size_t)nn * 512;
    }
    nx = nxt + go;
    int d = deg[base + nn];
    int cb = min(d, STRIDE);
    if (lane < cb) gl[wid][lane] = adj[(size_t)(base + nn) * STRIDE + lane];
    __syncthreads();
    float4 dv = *(const float4*)(den + (size_t)nn * 4);
    float inv0 = 1.f / fmaxf(dv.x, 1e-9f);
    float inv1 = 1.f / fmaxf(dv.y, 1e-9f);
    float inv2 = 1.f / fmaxf(dv.z, 1e-9f);
    float inv3 = 1.f / fmaxf(dv.w, 1e-9f);
    float acc[4][2] = {};
    for (int i = 0; i < cb; ++i) {
        uint2 es = gl[wid][i];
        float4 e4 = *(const float4*)(ex + (size_t)es.x * 4);
        unsigned xw = *(const unsigned*)(xs + (size_t)es.y * DD + lane * 2);
        float x0 = bf2f((unsigned short)(xw & 0xffff));
        float x1 = bf2f((unsigned short)(xw >> 16));
        float a0 = e4.x * inv0, a1 = e4.y * inv1, a2 = e4.z * inv2, a3 = e4.w * inv3;
        acc[0][0] += a0 * x0; acc[0][1] += a0 * x1;
        acc[1][0] += a1 * x0; acc[1][1] += a1 * x1;
        acc[2][0] += a2 * x0; acc[2][1] += a2 * x1;
        acc[3][0] += a3 * x0; acc[3][1] += a3 * x1;
    }
    if (d > STRIDE) {
        for (int e = heads[base + nn]; e >= 0; e = nx[e]) {
            int s = esrc[e];
            float4 e4 = *(const float4*)(ex + (size_t)e * 4);
            unsigned xw = *(const unsigned*)(xs + (size_t)s * DD + lane * 2);
            float x0 = bf2f((unsigned short)(xw & 0xffff));
            float x1 = bf2f((unsigned short)(xw >> 16));
            float a0 = e4.x * inv0, a1 = e4.y * inv1, a2 = e4.z * inv2, a3 = e4.w * inv3;
            acc[0][0] += a0 * x0; acc[0][1] += a0 * x1;
            acc[1][0] += a1 * x0; acc[1][1] += a1 * x1;
            acc[2][0] += a2 * x0; acc[2][1] += a2 * x1;
            acc[3][0] += a3 * x0; acc[3][1] += a3 * x1;
        }
    }
#pragma unroll
    for (int h = 0; h < 4; ++h) {
        unsigned o = (unsigned)f2bf(acc[h][0]) | ((unsigned)f2bf(acc[h][1]) << 16);
        *(unsigned*)(A2 + h * 128 + lane * 2) = o;
    }
}

// ---------------- bf16 MFMA GEMM device body ----------------
#define LDKP 40
template <int EPI, int OUTBF, int GATK>
__device__ __forceinline__ void gemm_body(
    const unsigned short* __restrict__ A, const unsigned short* __restrict__ Bt,
    void* __restrict__ C, int M, int N, int K,
    const float* __restrict__ bias, const float* __restrict__ g,
    const float* __restrict__ be, const unsigned short* __restrict__ addbf,
    const unsigned short* __restrict__ Axd, int bxx, int byy,
    unsigned short* As, unsigned short* Bs) {
    int tid = threadIdx.x;
    int wave = tid >> 6, lane = tid & 63;
    int wr = wave >> 1, wc = wave & 1;
    int row0 = byy * 128, col0 = bxx * 128;
    int l16 = lane & 15, khalf = (lane >> 4) * 8;
    f32x4 acc[4][4] = {};
    int r_0 = tid >> 2, ko = (tid & 3) * 8;
    int r_1 = r_0 + 64;
    for (int k0 = 0; k0 < K; k0 += 32) {
        __syncthreads();
        {
            int kk = k0 + ko;
            int ra = min(row0 + r_0, M - 1);
            uint4 va;
            if (GATK) va = (kk < 128) ? *(const uint4*)(A + (size_t)ra * 512 + col0 + kk)
                                      : *(const uint4*)(Axd + (size_t)ra * 128 + (kk - 128));
            else va = *(const uint4*)(A + (size_t)ra * K + kk);
            *(uint4*)(&As[r_0 * LDKP + ko]) = va;
            uint4 vb = *(const uint4*)(Bt + (size_t)(col0 + r_0) * K + kk);
            *(uint4*)(&Bs[r_0 * LDKP + ko]) = vb;
            ra = min(row0 + r_1, M - 1);
            if (GATK) va = (kk < 128) ? *(const uint4*)(A + (size_t)ra * 512 + col0 + kk)
                                      : *(const uint4*)(Axd + (size_t)ra * 128 + (kk - 128));
            else va = *(const uint4*)(A + (size_t)ra * K + kk);
            *(uint4*)(&As[r_1 * LDKP + ko]) = va;
            vb = *(const uint4*)(Bt + (size_t)(col0 + r_1) * K + kk);
            *(uint4*)(&Bs[r_1 * LDKP + ko]) = vb;
        }
        __syncthreads();
        bf16x8 af[4], bfr[4];
#pragma unroll
        for (int i = 0; i < 4; ++i)
            af[i] = *(const bf16x8*)(&As[(wr * 64 + i * 16 + l16) * LDKP + khalf]);
#pragma unroll
        for (int j = 0; j < 4; ++j)
            bfr[j] = *(const bf16x8*)(&Bs[(wc * 64 + j * 16 + l16) * LDKP + khalf]);
#pragma unroll
        for (int i = 0; i < 4; ++i)
#pragma unroll
            for (int j = 0; j < 4; ++j)
                acc[i][j] = __builtin_amdgcn_mfma_f32_16x16x32_bf16(af[i], bfr[j], acc[i][j], 0, 0, 0);
    }
    int rq = (lane >> 4) * 4;
#pragma unroll
    for (int i = 0; i < 4; ++i) {
#pragma unroll
        for (int reg = 0; reg < 4; ++reg) {
            int r = row0 + wr * 64 + i * 16 + rq + reg;
            if (r >= M) continue;
#pragma unroll
            for (int j = 0; j < 4; ++j) {
                int c = col0 + wc * 64 + j * 16 + l16;
                float v = acc[i][j][reg];
                size_t idx = (size_t)r * N + c;
                v += bias[c];
                if (EPI == 2) {
                    v = g[c] * (v * BN_INV_C) + be[c];
                    v = fmaxf(v, 0.f);
                }
                if (EPI == 3) {
                    ((float*)C)[idx] = v + bf2f(addbf[idx]);
                } else if (OUTBF) {
                    ((unsigned short*)C)[idx] = f2bf(v);
                } else {
                    ((float*)C)[idx] = v;
                }
            }
        }
    }
}

#define NBA 782
#define NBG 196

// GINE GEMM1 both relations: 1564 + 392 blocks
__global__ __launch_bounds__(256) void k_gemm1(
    const unsigned short* h0A, const unsigned short* h0G,
    const unsigned short* WtB1, const unsigned short* WtO1,
    const float* bb1, const float* bg1, const float* bbe1,
    const float* ob1, const float* og1, const float* obe1,
    unsigned short* R4a, unsigned short* R4g) {
    __shared__ unsigned short As[128 * LDKP];
    __shared__ unsigned short Bs[128 * LDKP];
    int b = blockIdx.x;
    if (b < 2 * NBA)
        gemm_body<2, 1, 0>(h0A, WtB1, R4a, N_A, 256, 128, bb1, bg1, bbe1, nullptr, nullptr,
                           b & 1, b >> 1, As, Bs);
    else {
        int b2 = b - 2 * NBA;
        gemm_body<2, 1, 0>(h0G, WtO1, R4g, N_G, 256, 128, ob1, og1, obe1, nullptr, nullptr,
                           b2 & 1, b2 >> 1, As, Bs);
    }
}

// GINE GEMM2 (both) + GATK GEMMs (both): 782+196+3128+784 = 4890 blocks
__global__ __launch_bounds__(256) void k_gemm_mid(
    const unsigned short* R4a, const unsigned short* R4g,
    const unsigned short* WtB2, const unsigned short* WtO2,
    const float* bb2, const float* ob2,
    unsigned short* G1a, unsigned short* G1g,
    const unsigned short* A2r, const unsigned short* A2p,
    const unsigned short* xAb, const unsigned short* xGb,
    const unsigned short* WtR, const unsigned short* WtP,
    const float* rbias, const float* rg, const float* rb,
    const float* pbias, const float* pg, const float* pb,
    unsigned short* R3r, unsigned short* R3p) {
    __shared__ unsigned short As[128 * LDKP];
    __shared__ unsigned short Bs[128 * LDKP];
    int b = blockIdx.x;
    if (b < NBA)
        gemm_body<1, 1, 0>(R4a, WtB2, G1a, N_A, 128, 256, bb2, nullptr, nullptr, nullptr, nullptr,
                           0, b, As, Bs);
    else if (b < NBA + NBG)
        gemm_body<1, 1, 0>(R4g, WtO2, G1g, N_G, 128, 256, ob2, nullptr, nullptr, nullptr, nullptr,
                           0, b - NBA, As, Bs);
    else if (b < NBA + NBG + 4 * NBA) {
        int b3 = b - (NBA + NBG);
        gemm_body<2, 1, 1>(A2r, WtR, R3r, N_A, 512, 256, rbias, rg, rb, nullptr, xAb,
                           b3 & 3, b3 >> 2, As, Bs);
    } else {
        int b4 = b - (NBA + NBG + 4 * NBA);
        gemm_body<2, 1, 1>(A2p, WtP, R3p, N_G, 512, 256, pbias, pg, pb, nullptr, xGb,
                           b4 & 3, b4 >> 2, As, Bs);
    }
}

// Wout GEMMs (both): 978 blocks, single f32 write of d_out
__global__ __launch_bounds__(256) void k_gemm_out(
    const unsigned short* R3r, const unsigned short* R3p,
    const unsigned short* WtRo, const unsigned short* WtPo,
    const float* rbout, const float* pbout,
    const unsigned short* G1a, const unsigned short* G1g,
    float* out) {
    __shared__ unsigned short As[128 * LDKP];
    __shared__ unsigned short Bs[128 * LDKP];
    int b = blockIdx.x;
    if (b < NBA)
        gemm_body<3, 0, 0>(R3r, WtRo, out, N_A, 128, 512, rbout, nullptr, nullptr, G1a, nullptr,
                           0, b, As, Bs);
    else
        gemm_body<3, 0, 0>(R3p, WtPo, out + (size_t)N_A * DD, N_G, 128, 512, pbout, nullptr, nullptr,
                           G1g, nullptr, 0, b - NBA, As, Bs);
}

extern "C" void kernel_launch(void* const* d_in, const int* in_sizes, int n_in,
                              void* d_out, int out_size, void* d_ws, size_t ws_size,
                              hipStream_t stream) {
    const float* x_atom = (const float*)d_in[0];
    const float* x_group = (const float*)d_in[1];
    const float* ef_bond = (const float*)d_in[2];
    const float* ef_ov = (const float*)d_in[3];
    const int* bond_src = (const int*)d_in[4];
    const int* bond_dst = (const int*)d_in[5];
    const int* ov_src = (const int*)d_in[6];
    const int* ov_dst = (const int*)d_in[7];
    const int* ref_src = (const int*)d_in[8];
    const int* ref_dst = (const int*)d_in[9];
    const int* pool_src = (const int*)d_in[10];
    const int* pool_dst = (const int*)d_in[11];
    const float* b_eps = (const float*)d_in[12];
    const float* b_W1 = (const float*)d_in[13];
    const float* b_b1 = (const float*)d_in[14];
    const float* b_g1 = (const float*)d_in[15];
    const float* b_be1 = (const float*)d_in[16];
    const float* b_W2 = (const float*)d_in[17];
    const float* b_b2 = (const float*)d_in[18];
    const float* o_eps = (const float*)d_in[19];
    const float* o_W1 = (const float*)d_in[20];
    const float* o_b1 = (const float*)d_in[21];
    const float* o_g1 = (const float*)d_in[22];
    const float* o_be1 = (const float*)d_in[23];
    const float* o_W2 = (const float*)d_in[24];
    const float* o_b2 = (const float*)d_in[25];
    const float* r_Wfc = (const float*)d_in[26];
    const float* r_al = (const float*)d_in[27];
    const float* r_ar = (const float*)d_in[28];
    const float* r_Wres = (const float*)d_in[29];
    const float* r_bias = (const float*)d_in[30];
    const float* r_g = (const float*)d_in[31];
    const float* r_b = (const float*)d_in[32];
    const float* r_Wout = (const float*)d_in[33];
    const float* r_bout = (const float*)d_in[34];
    const float* p_Wfc = (const float*)d_in[35];
    const float* p_al = (const float*)d_in[36];
    const float* p_ar = (const float*)d_in[37];
    const float* p_Wres = (const float*)d_in[38];
    const float* p_bias = (const float*)d_in[39];
    const float* p_g = (const float*)d_in[40];
    const float* p_b = (const float*)d_in[41];
    const float* p_Wout = (const float*)d_in[42];
    const float* p_bout = (const float*)d_in[43];

    float* out = (float*)d_out;
    char* wsb = (char*)d_ws;
    unsigned short* xAb = (unsigned short*)(wsb + 0);             // 25.6 MB
    unsigned short* xGb = (unsigned short*)(wsb + 26000000);      // 6.4 MB
    unsigned short* WtB1 = (unsigned short*)(wsb + 33000000);     // weight slots
    unsigned short* WtB2 = WtB1 + 32768;
    unsigned short* WtO1 = WtB2 + 32768;
    unsigned short* WtO2 = WtO1 + 32768;
    unsigned short* WtR  = WtO2 + 32768;   // 512x256 (Wfc|Wres)
    unsigned short* WtRo = WtR + 131072;   // 128x512
    unsigned short* WtP  = WtRo + 65536;   // 512x256
    unsigned short* WtPo = WtP + 131072;   // 128x512
    float* wv   = (float*)(wsb + 34100000);                       // 4x512 f32
    int* heads  = (int*)(wsb + 36300000);                         // 250k int
    int* nxt    = (int*)(wsb + 37400000);                         // 900k int
    unsigned short* h0A = (unsigned short*)(wsb + 41100000);      // 25.6 MB
    unsigned short* h0G = (unsigned short*)(wsb + 66800000);      // 6.4 MB
    unsigned short* R4a = (unsigned short*)(wsb + 73300000);      // 51.2 MB
    unsigned short* G1a = (unsigned short*)(wsb + 124600000);     // 25.6 MB
    unsigned short* G1g = (unsigned short*)(wsb + 150300000);     // 6.4 MB
    unsigned short* A2r = (unsigned short*)(wsb + 156800000);     // 102.4 MB
    unsigned short* A2p = (unsigned short*)(wsb + 259300000);     // 25.6 MB
    unsigned short* R3r = (unsigned short*)(wsb + 285000000);     // 102.4 MB
    unsigned short* R3p = (unsigned short*)(wsb + 387500000);     // 25.6 MB
    uint2* adj  = (uint2*)(wsb + 414000000);                      // 128 MB
    int* deg    = (int*)(wsb + 543000000);                        // 1 MB
    float* F    = (float*)(wsb + 544000000);                      // logit/ex block
    float* elR  = F;               // N_G*4
    float* elP  = F + 100000;      // N_A*4
    float* erR  = F + 500000;      // N_A*4
    float* erP  = F + 900000;      // N_G*4
    float* denR = F + 1000000;     // N_A*4
    float* denP = F + 1400000;     // N_G*4
    float* exR  = F + 1500000;     // E_R*4
    float* exP  = F + 2300000;     // E_P*4
    unsigned short* R4g = (unsigned short*)(wsb + 560000000);     // 12.8 MB

    // memsets for prep
    hipMemsetAsync(deg, 0, NSLOT * 4, stream);
    hipMemsetAsync(heads, 0xFF, NSLOT * 4, stream);
    hipMemsetAsync(denR, 0, 500000 * 4, stream);

    // 1. prep: xcast + wcast + war + adj_fill
    PrepArgs pa;
    pa.xa = x_atom; pa.xg = x_group; pa.xab = xAb; pa.xgb = xGb;
    pa.wc[0] = {b_W1, WtB1, 128, 256, 128, 0};
    pa.wc[1] = {b_W2, WtB2, 256, 128, 256, 0};
    pa.wc[2] = {o_W1, WtO1, 128, 256, 128, 0};
    pa.wc[3] = {o_W2, WtO2, 256, 128, 256, 0};
    pa.wc[4] = {r_Wfc, WtR, 128, 512, 256, 0};
    pa.wc[5] = {r_Wres, WtR, 128, 512, 256, 128};
    pa.wc[6] = {r_Wout, WtRo, 512, 128, 512, 0};
    pa.wc[7] = {p_Wfc, WtP, 128, 512, 256, 0};
    pa.wc[8] = {p_Wres, WtP, 128, 512, 256, 128};
    pa.wc[9] = {p_Wout, WtPo, 512, 128, 512, 0};
    pa.rWfc = r_Wfc; pa.ral = r_al; pa.rar = r_ar;
    pa.pWfc = p_Wfc; pa.pal = p_al; pa.par = p_ar; pa.wv = wv;
    pa.bs = bond_src; pa.bd = bond_dst; pa.os = ov_src; pa.od = ov_dst;
    pa.rs = ref_src; pa.rd = ref_dst; pa.ps = pool_src; pa.pd = pool_dst;
    pa.deg = deg; pa.adj = adj; pa.heads = heads; pa.nxt = nxt;
    k_prep<<<PB_XC + PB_WC + PB_WAR + 3516, 256, 0, stream>>>(pa);

    // 2. GINE gather + node logits
    k_gather_logit<<<31250 + 1954, 256, 0, stream>>>(
        xAb, xGb, ef_bond, ef_ov, bond_src, ov_src, deg, adj, heads, nxt,
        b_eps, o_eps, h0A, h0G, wv, elR, elP, erR, erP);

    // 3. edge exp + denominators
    k_exp_all<<<6250, 256, 0, stream>>>(elR, erR, elP, erP,
        ref_src, ref_dst, pool_src, pool_dst, exR, exP, denR, denP);

    // 4. GINE GEMM1 (both relations)
    k_gemm1<<<2 * NBA + 2 * NBG, 256, 0, stream>>>(h0A, h0G, WtB1, WtO1,
        b_b1, b_g1, b_be1, o_b1, o_g1, o_be1, R4a, R4g);

    // 5. GAT aggregation
    k_att_gather_all<<<31250, 256, 0, stream>>>(xAb, xGb, exR, exP, denR, denP, ref_src, pool_src,
                                                deg, adj, heads, nxt, A2r, A2p);

    // 6. GINE GEMM2 + GATK GEMMs
    k_gemm_mid<<<NBA + NBG + 4 * NBA + 4 * NBG, 256, 0, stream>>>(
        R4a, R4g, WtB2, WtO2, b_b2, o_b2, G1a, G1g,
        A2r, A2p, xAb, xGb, WtR, WtP,
        r_bias, r_g, r_b, p_bias, p_g, p_b, R3r, R3p);

    // 7. Wout GEMMs -> d_out
    k_gemm_out<<<NBA + NBG, 256, 0, stream>>>(R3r, R3p, WtRo, WtPo, r_bout, p_bout,
                                              G1a, G1g, out);
}

// Round 11
// 540.819 us; speedup vs baseline: 1.1449x; 1.0027x over previous
//
#include <hip/hip_runtime.h>
#include <hip/hip_bf16.h>

#define N_A 100000
#define N_G 25000
#define DD 128
#define E_B 400000
#define E_O 100000
#define E_R 200000
#define E_P 200000
#define EALL 900000
#define NSLOT 250000
#define STRIDE 64

static constexpr float BN_INV_C = 0.99999500003749969f; // 1/sqrt(1+1e-5)

typedef __attribute__((ext_vector_type(8))) short bf16x8;
typedef __attribute__((ext_vector_type(4))) float f32x4;

__device__ __forceinline__ unsigned short f2bf(float f) {
    unsigned u = __float_as_uint(f);
    unsigned r = (u + 0x7FFFu + ((u >> 16) & 1u)) >> 16;
    return (unsigned short)r;
}
__device__ __forceinline__ float bf2f(unsigned short s) {
    return __uint_as_float(((unsigned)s) << 16);
}
__device__ __forceinline__ float lrelu(float v) { return v > 0.f ? v : 0.2f * v; }

// async global->LDS 16B: LDS dest = (wave-uniform base) + lane*16
__device__ __forceinline__ void gload16(const unsigned short* g, unsigned short* l) {
    __builtin_amdgcn_global_load_lds(
        (const __attribute__((address_space(1))) void*)g,
        (__attribute__((address_space(3))) void*)l, 16, 0, 0);
}

// ---------------- prep: xcast + wcast + war + adj_fill in one launch ----------------
struct WcSeg { const float* src; unsigned short* dst; int K; int N; int ldk; int off; };
struct PrepArgs {
    const float* xa; const float* xg;
    unsigned short* xab; unsigned short* xgb;
    WcSeg wc[10];
    const float* rWfc; const float* ral; const float* rar;
    const float* pWfc; const float* pal; const float* par;
    float* wv;
    const int* bs; const int* bd; const int* os; const int* od;
    const int* rs; const int* rd; const int* ps; const int* pd;
    int* deg; uint2* adj; int* heads; int* nxt;
};

#define PB_XC 15625
#define PB_WC 2560
#define PB_WAR 8

__global__ __launch_bounds__(256) void k_prep(PrepArgs p) {
    int bx = blockIdx.x, tid = threadIdx.x;
    if (bx < PB_XC) {
        int t = bx * 256 + tid;
        if (t < N_A * 32) {
            float4 v = *(const float4*)(p.xa + (size_t)t * 4);
            ushort4 o; o.x = f2bf(v.x); o.y = f2bf(v.y); o.z = f2bf(v.z); o.w = f2bf(v.w);
            *(ushort4*)(p.xab + (size_t)t * 4) = o;
        } else {
            int t2 = t - N_A * 32;
            if (t2 < N_G * 32) {
                float4 v = *(const float4*)(p.xg + (size_t)t2 * 4);
                ushort4 o; o.x = f2bf(v.x); o.y = f2bf(v.y); o.z = f2bf(v.z); o.w = f2bf(v.w);
                *(ushort4*)(p.xgb + (size_t)t2 * 4) = o;
            }
        }
    } else if (bx < PB_XC + PB_WC) {
        int b2 = bx - PB_XC;
        WcSeg sg = p.wc[b2 >> 8];
        int t = ((b2 & 255) << 8) + tid;
        if (t < sg.K * sg.N) {
            int n = t % sg.N, k = t / sg.N;
            sg.dst[(size_t)n * sg.ldk + sg.off + k] = f2bf(sg.src[t]);
        }
    } else if (bx < PB_XC + PB_WC + PB_WAR) {
        int b3 = bx - (PB_XC + PB_WC);
        int bsel = b3 >> 1;
        int t = ((b3 & 1) << 8) + tid;   // 512 threads per bsel
        const float* W = bsel < 2 ? p.rWfc : p.pWfc;
        const float* vec = bsel == 0 ? p.ral : bsel == 1 ? p.rar : bsel == 2 ? p.pal : p.par;
        int k = t >> 2, h = t & 3;
        const float* wr = W + (size_t)k * 512 + h * 128;
        const float* av = vec + h * 128;
        float s = 0.f;
        for (int d = 0; d < 128; ++d) s += wr[d] * av[d];
        p.wv[bsel * 512 + t] = s;
    } else {
        int t = (bx - (PB_XC + PB_WC + PB_WAR)) * 256 + tid;
        int e, base, go; const int* S; const int* D;
        if (t < E_B) { e = t; S = p.bs; D = p.bd; base = 0; go = 0; }
        else if (t < E_B + E_O) { e = t - E_B; S = p.os; D = p.od; base = 100000; go = E_B; }
        else if (t < E_B + E_O + E_R) { e = t - (E_B + E_O); S = p.rs; D = p.rd; base = 125000; go = E_B + E_O; }
        else if (t < EALL) { e = t - (E_B + E_O + E_R); S = p.ps; D = p.pd; base = 225000; go = E_B + E_O + E_R; }
        else return;
        int d = D[e], s = S[e];
        int ns = base + d;
        int pos = atomicAdd(&p.deg[ns], 1);
        if (pos < STRIDE) p.adj[(size_t)ns * STRIDE + pos] = make_uint2((unsigned)e, (unsigned)s);
        else p.nxt[go + e] = atomicExch(&p.heads[ns], e);
    }
}

// ---------------- GINE gather (wave/node) + node logits, one launch ----------------
__global__ __launch_bounds__(256) void k_gather_logit(
    const unsigned short* __restrict__ xAb, const unsigned short* __restrict__ xGb,
    const float* __restrict__ efB, const float* __restrict__ efO,
    const int* __restrict__ bsrc, const int* __restrict__ osrc,
    const int* __restrict__ deg, const uint2* __restrict__ adj,
    const int* __restrict__ heads, const int* __restrict__ nxt,
    const float* __restrict__ beps, const float* __restrict__ oeps,
    unsigned short* __restrict__ h0A, unsigned short* __restrict__ h0G,
    const float* __restrict__ wv,
    float* __restrict__ elR, float* __restrict__ elP,
    float* __restrict__ erR, float* __restrict__ erP) {
    __shared__ uint2 gl[4][STRIDE];
    int bx = blockIdx.x;
    if (bx < 31250) {
        int wid = threadIdx.x >> 6, lane = threadIdx.x & 63;
        int n = bx * 4 + wid;
        const unsigned short* xs; const unsigned short* xdrow; const float* ef;
        const int* esrc; const int* nx; float ep; unsigned short* outp; int nn, base, go;
        if (n < N_A) {
            nn = n; xs = xAb; xdrow = xAb + (size_t)n * DD; ef = efB; esrc = bsrc;
            base = 0; go = 0; ep = 1.0f + beps[0]; outp = h0A + (size_t)n * DD;
        } else {
            nn = n - N_A; xs = xGb; xdrow = xGb + (size_t)nn * DD; ef = efO; esrc = osrc;
            base = 100000; go = E_B; ep = 1.0f + oeps[0]; outp = h0G + (size_t)nn * DD;
        }
        nx = nxt + go;
        int d = deg[base + nn];
        int cb = min(d, STRIDE);
        if (lane < cb) gl[wid][lane] = adj[(size_t)(base + nn) * STRIDE + lane];
        __syncthreads();
        float2 acc = make_float2(0.f, 0.f);
        for (int i = 0; i < cb; ++i) {
            uint2 es = gl[wid][i];
            unsigned xa = *(const unsigned*)(xs + (size_t)es.y * DD + lane * 2);
            float2 ev = *(const float2*)(ef + (size_t)es.x * DD + lane * 2);
            acc.x += fmaxf(bf2f((unsigned short)(xa & 0xffff)) + ev.x, 0.f);
            acc.y += fmaxf(bf2f((unsigned short)(xa >> 16)) + ev.y, 0.f);
        }
        if (d > STRIDE) {
            for (int e = heads[base + nn]; e >= 0; e = nx[e]) {
                int s = esrc[e];
                unsigned xa = *(const unsigned*)(xs + (size_t)s * DD + lane * 2);
                float2 ev = *(const float2*)(ef + (size_t)e * DD + lane * 2);
                acc.x += fmaxf(bf2f((unsigned short)(xa & 0xffff)) + ev.x, 0.f);
                acc.y += fmaxf(bf2f((unsigned short)(xa >> 16)) + ev.y, 0.f);
            }
        }
        unsigned xd = *(const unsigned*)(xdrow + lane * 2);
        float rx = ep * bf2f((unsigned short)(xd & 0xffff)) + acc.x;
        float ry = ep * bf2f((unsigned short)(xd >> 16)) + acc.y;
        *(unsigned*)(outp + lane * 2) = (unsigned)f2bf(rx) | ((unsigned)f2bf(ry) << 16);
    } else {
        int t = (bx - 31250) * 256 + threadIdx.x;
        const unsigned short* xr; const float* wl; const float* wr_; float* ol; float* orr; int idx;
        if (t < N_A * 4) {
            idx = t; xr = xAb + (size_t)(t >> 2) * DD; wl = wv + 1024; wr_ = wv + 512;
            ol = elP; orr = erR;
        } else {
            int t2 = t - N_A * 4;
            if (t2 >= N_G * 4) return;
            idx = t2; xr = xGb + (size_t)(t2 >> 2) * DD; wl = wv; wr_ = wv + 1536;
            ol = elR; orr = erP;
        }
        int h = idx & 3;
        float sl = 0.f, sr = 0.f;
#pragma unroll
        for (int k = 0; k < DD; k += 8) {
            uint4 w = *(const uint4*)(xr + k);
            unsigned wa[4] = {w.x, w.y, w.z, w.w};
#pragma unroll
            for (int q = 0; q < 4; ++q) {
                float x0 = bf2f((unsigned short)(wa[q] & 0xffff));
                float x1 = bf2f((unsigned short)(wa[q] >> 16));
                int k0 = (k + q * 2) * 4 + h, k1 = (k + q * 2 + 1) * 4 + h;
                sl += x0 * wl[k0] + x1 * wl[k1];
                sr += x0 * wr_[k0] + x1 * wr_[k1];
            }
        }
        ol[idx] = sl;
        orr[idx] = sr;
    }
}

// ---------------- edge-parallel exp + denominator ----------------
__global__ void k_exp_all(const float* __restrict__ elR, const float* __restrict__ erR,
                          const float* __restrict__ elP, const float* __restrict__ erP,
                          const int* __restrict__ rs, const int* __restrict__ rd,
                          const int* __restrict__ ps, const int* __restrict__ pd,
                          float* __restrict__ exR, float* __restrict__ exP,
                          float* __restrict__ denR, float* __restrict__ denP) {
    int t = blockIdx.x * blockDim.x + threadIdx.x;
    if (t < E_R * 4) {
        int e = t >> 2, h = t & 3;
        float v = lrelu(elR[rs[e] * 4 + h] + erR[rd[e] * 4 + h]);
        float x = __expf(v);
        exR[t] = x;
        atomicAdd(&denR[rd[e] * 4 + h], x);
    } else {
        int t2 = t - E_R * 4;
        if (t2 >= E_P * 4) return;
        int e = t2 >> 2, h = t2 & 3;
        float v = lrelu(elP[ps[e] * 4 + h] + erP[pd[e] * 4 + h]);
        float x = __expf(v);
        exP[t2] = x;
        atomicAdd(&denP[pd[e] * 4 + h], x);
    }
}

// ---------------- GAT gather: pure weighted aggregation ----------------
__global__ __launch_bounds__(256) void k_att_gather_all(
    const unsigned short* __restrict__ xAb, const unsigned short* __restrict__ xGb,
    const float* __restrict__ exR, const float* __restrict__ exP,
    const float* __restrict__ denR, const float* __restrict__ denP,
    const int* __restrict__ rsrc, const int* __restrict__ psrc,
    const int* __restrict__ deg, const uint2* __restrict__ adj,
    const int* __restrict__ heads, const int* __restrict__ nxt,
    unsigned short* __restrict__ A2r, unsigned short* __restrict__ A2p) {
    int wid = threadIdx.x >> 6, lane = threadIdx.x & 63;
    int n = blockIdx.x * 4 + wid;
    __shared__ uint2 gl[4][STRIDE];
    const unsigned short* xs; const float* ex; const float* den;
    const int* esrc; const int* nx; unsigned short* A2; int nn, base, go;
    if (n < N_A) {
        nn = n; xs = xGb; ex = exR; den = denR; esrc = rsrc;
        base = 125000; go = E_B + E_O; A2 = A2r + (size_t)n * 512;
    } else {
        nn = n - N_A; xs = xAb; ex = exP; den = denP; esrc = psrc;
        base = 225000; go = E_B + E_O + E_R; A2 = A2p + (size_t)nn * 512;
    }
    nx = nxt + go;
    int d = deg[base + nn];
    int cb = min(d, STRIDE);
    if (lane < cb) gl[wid][lane] = adj[(size_t)(base + nn) * STRIDE + lane];
    __syncthreads();
    float4 dv = *(const float4*)(den + (size_t)nn * 4);
    float inv0 = 1.f / fmaxf(dv.x, 1e-9f);
    float inv1 = 1.f / fmaxf(dv.y, 1e-9f);
    float inv2 = 1.f / fmaxf(dv.z, 1e-9f);
    float inv3 = 1.f / fmaxf(dv.w, 1e-9f);
    float acc[4][2] = {};
    for (int i = 0; i < cb; ++i) {
        uint2 es = gl[wid][i];
        float4 e4 = *(const float4*)(ex + (size_t)es.x * 4);
        unsigned xw = *(const unsigned*)(xs + (size_t)es.y * DD + lane * 2);
        float x0 = bf2f((unsigned short)(xw & 0xffff));
        float x1 = bf2f((unsigned short)(xw >> 16));
        float a0 = e4.x * inv0, a1 = e4.y * inv1, a2 = e4.z * inv2, a3 = e4.w * inv3;
        acc[0][0] += a0 * x0; acc[0][1] += a0 * x1;
        acc[1][0] += a1 * x0; acc[1][1] += a1 * x1;
        acc[2][0] += a2 * x0; acc[2][1] += a2 * x1;
        acc[3][0] += a3 * x0; acc[3][1] += a3 * x1;
    }
    if (d > STRIDE) {
        for (int e = heads[base + nn]; e >= 0; e = nx[e]) {
            int s = esrc[e];
            float4 e4 = *(const float4*)(ex + (size_t)e * 4);
            unsigned xw = *(const unsigned*)(xs + (size_t)s * DD + lane * 2);
            float x0 = bf2f((unsigned short)(xw & 0xffff));
            float x1 = bf2f((unsigned short)(xw >> 16));
            float a0 = e4.x * inv0, a1 = e4.y * inv1, a2 = e4.z * inv2, a3 = e4.w * inv3;
            acc[0][0] += a0 * x0; acc[0][1] += a0 * x1;
            acc[1][0] += a1 * x0; acc[1][1] += a1 * x1;
            acc[2][0] += a2 * x0; acc[2][1] += a2 * x1;
            acc[3][0] += a3 * x0; acc[3][1] += a3 * x1;
        }
    }
#pragma unroll
    for (int h = 0; h < 4; ++h) {
        unsigned o = (unsigned)f2bf(acc[h][0]) | ((unsigned)f2bf(acc[h][1]) << 16);
        *(unsigned*)(A2 + h * 128 + lane * 2) = o;
    }
}

// ---------------- bf16 MFMA GEMM device body (global_load_lds + src-side swizzle) ----------------
// LDS tile [128 rows][32 shorts], unpadded. 16B-unit swizzle: phys_u = log_u ^ SW(row),
// SW(row) = (row ^ (row>>2)) & 3. DMA writes linearly (lane*16B), so the permutation is
// applied to the per-lane GLOBAL source; reads use the same XOR. Max 2 lanes/bank (free).
template <int EPI, int OUTBF, int GATK>
__device__ __forceinline__ void gemm_body(
    const unsigned short* __restrict__ A, const unsigned short* __restrict__ Bt,
    void* __restrict__ C, int M, int N, int K,
    const float* __restrict__ bias, const float* __restrict__ g,
    const float* __restrict__ be, const unsigned short* __restrict__ addbf,
    const unsigned short* __restrict__ Axd, int bxx, int byy,
    unsigned short* As, unsigned short* Bs) {
    int tid = threadIdx.x;
    int wave = tid >> 6, lane = tid & 63;
    int wr = wave >> 1, wc = wave & 1;
    int row0 = byy * 128, col0 = bxx * 128;
    int l16 = lane & 15, q = lane >> 4;
    // staging: wave covers rows [wave*16, wave*16+16) and +64; lane fetches logical unit swl
    int r0s = wave * 16 + (lane >> 2);
    int r1s = r0s + 64;
    int swl = (lane ^ (lane >> 2) ^ (lane >> 4)) & 3;   // logical 16B unit this lane fetches
    int swr = (l16 ^ (l16 >> 2)) & 3;                   // read-side XOR
    unsigned short* ldsA0 = As + wave * 512;
    unsigned short* ldsA1 = As + 2048 + wave * 512;
    unsigned short* ldsB0 = Bs + wave * 512;
    unsigned short* ldsB1 = Bs + 2048 + wave * 512;
    f32x4 acc[4][4] = {};
    for (int k0 = 0; k0 < K; k0 += 32) {
        __syncthreads();
        {
            int kk = k0 + swl * 8;
            int ra0 = min(row0 + r0s, M - 1);
            int ra1 = min(row0 + r1s, M - 1);
            const unsigned short *pa0, *pa1;
            if (GATK) {
                if (k0 < 128) {
                    pa0 = A + (size_t)ra0 * 512 + col0 + kk;
                    pa1 = A + (size_t)ra1 * 512 + col0 + kk;
                } else {
                    pa0 = Axd + (size_t)ra0 * 128 + (kk - 128);
                    pa1 = Axd + (size_t)ra1 * 128 + (kk - 128);
                }
            } else {
                pa0 = A + (size_t)ra0 * K + kk;
                pa1 = A + (size_t)ra1 * K + kk;
            }
            gload16(pa0, ldsA0);
            gload16(pa1, ldsA1);
            gload16(Bt + (size_t)(col0 + r0s) * K + kk, ldsB0);
            gload16(Bt + (size_t)(col0 + r1s) * K + kk, ldsB1);
        }
        __syncthreads();
        bf16x8 af[4], bfr[4];
#pragma unroll
        for (int i = 0; i < 4; ++i) {
            int row = wr * 64 + i * 16 + l16;
            af[i] = *(const bf16x8*)(&As[row * 32 + ((q ^ swr) * 8)]);
        }
#pragma unroll
        for (int j = 0; j < 4; ++j) {
            int row = wc * 64 + j * 16 + l16;
            bfr[j] = *(const bf16x8*)(&Bs[row * 32 + ((q ^ swr) * 8)]);
        }
#pragma unroll
        for (int i = 0; i < 4; ++i)
#pragma unroll
            for (int j = 0; j < 4; ++j)
                acc[i][j] = __builtin_amdgcn_mfma_f32_16x16x32_bf16(af[i], bfr[j], acc[i][j], 0, 0, 0);
    }
    int rq = (lane >> 4) * 4;
#pragma unroll
    for (int i = 0; i < 4; ++i) {
#pragma unroll
        for (int reg = 0; reg < 4; ++reg) {
            int r = row0 + wr * 64 + i * 16 + rq + reg;
            if (r >= M) continue;
#pragma unroll
            for (int j = 0; j < 4; ++j) {
                int c = col0 + wc * 64 + j * 16 + l16;
                float v = acc[i][j][reg];
                size_t idx = (size_t)r * N + c;
                v += bias[c];
                if (EPI == 2) {
                    v = g[c] * (v * BN_INV_C) + be[c];
                    v = fmaxf(v, 0.f);
                }
                if (EPI == 3) {
                    ((float*)C)[idx] = v + bf2f(addbf[idx]);
                } else if (OUTBF) {
                    ((unsigned short*)C)[idx] = f2bf(v);
                } else {
                    ((float*)C)[idx] = v;
                }
            }
        }
    }
}

#define NBA 782
#define NBG 196

// GINE GEMM1 both relations: 1564 + 392 blocks
__global__ __launch_bounds__(256) void k_gemm1(
    const unsigned short* h0A, const unsigned short* h0G,
    const unsigned short* WtB1, const unsigned short* WtO1,
    const float* bb1, const float* bg1, const float* bbe1,
    const float* ob1, const float* og1, const float* obe1,
    unsigned short* R4a, unsigned short* R4g) {
    __shared__ unsigned short As[4096];
    __shared__ unsigned short Bs[4096];
    int b = blockIdx.x;
    if (b < 2 * NBA)
        gemm_body<2, 1, 0>(h0A, WtB1, R4a, N_A, 256, 128, bb1, bg1, bbe1, nullptr, nullptr,
                           b & 1, b >> 1, As, Bs);
    else {
        int b2 = b - 2 * NBA;
        gemm_body<2, 1, 0>(h0G, WtO1, R4g, N_G, 256, 128, ob1, og1, obe1, nullptr, nullptr,
                           b2 & 1, b2 >> 1, As, Bs);
    }
}

// GINE GEMM2 (both) + GATK GEMMs (both): 782+196+3128+784 = 4890 blocks
__global__ __launch_bounds__(256) void k_gemm_mid(
    const unsigned short* R4a, const unsigned short* R4g,
    const unsigned short* WtB2, const unsigned short* WtO2,
    const float* bb2, const float* ob2,
    unsigned short* G1a, unsigned short* G1g,
    const unsigned short* A2r, const unsigned short* A2p,
    const unsigned short* xAb, const unsigned short* xGb,
    const unsigned short* WtR, const unsigned short* WtP,
    const float* rbias, const float* rg, const float* rb,
    const float* pbias, const float* pg, const float* pb,
    unsigned short* R3r, unsigned short* R3p) {
    __shared__ unsigned short As[4096];
    __shared__ unsigned short Bs[4096];
    int b = blockIdx.x;
    if (b < NBA)
        gemm_body<1, 1, 0>(R4a, WtB2, G1a, N_A, 128, 256, bb2, nullptr, nullptr, nullptr, nullptr,
                           0, b, As, Bs);
    else if (b < NBA + NBG)
        gemm_body<1, 1, 0>(R4g, WtO2, G1g, N_G, 128, 256, ob2, nullptr, nullptr, nullptr, nullptr,
                           0, b - NBA, As, Bs);
    else if (b < NBA + NBG + 4 * NBA) {
        int b3 = b - (NBA + NBG);
        gemm_body<2, 1, 1>(A2r, WtR, R3r, N_A, 512, 256, rbias, rg, rb, nullptr, xAb,
                           b3 & 3, b3 >> 2, As, Bs);
    } else {
        int b4 = b - (NBA + NBG + 4 * NBA);
        gemm_body<2, 1, 1>(A2p, WtP, R3p, N_G, 512, 256, pbias, pg, pb, nullptr, xGb,
                           b4 & 3, b4 >> 2, As, Bs);
    }
}

// Wout GEMMs (both): 978 blocks, single f32 write of d_out
__global__ __launch_bounds__(256) void k_gemm_out(
    const unsigned short* R3r, const unsigned short* R3p,
    const unsigned short* WtRo, const unsigned short* WtPo,
    const float* rbout, const float* pbout,
    const unsigned short* G1a, const unsigned short* G1g,
    float* out) {
    __shared__ unsigned short As[4096];
    __shared__ unsigned short Bs[4096];
    int b = blockIdx.x;
    if (b < NBA)
        gemm_body<3, 0, 0>(R3r, WtRo, out, N_A, 128, 512, rbout, nullptr, nullptr, G1a, nullptr,
                           0, b, As, Bs);
    else
        gemm_body<3, 0, 0>(R3p, WtPo, out + (size_t)N_A * DD, N_G, 128, 512, pbout, nullptr, nullptr,
                           G1g, nullptr, 0, b - NBA, As, Bs);
}

extern "C" void kernel_launch(void* const* d_in, const int* in_sizes, int n_in,
                              void* d_out, int out_size, void* d_ws, size_t ws_size,
                              hipStream_t stream) {
    const float* x_atom = (const float*)d_in[0];
    const float* x_group = (const float*)d_in[1];
    const float* ef_bond = (const float*)d_in[2];
    const float* ef_ov = (const float*)d_in[3];
    const int* bond_src = (const int*)d_in[4];
    const int* bond_dst = (const int*)d_in[5];
    const int* ov_src = (const int*)d_in[6];
    const int* ov_dst = (const int*)d_in[7];
    const int* ref_src = (const int*)d_in[8];
    const int* ref_dst = (const int*)d_in[9];
    const int* pool_src = (const int*)d_in[10];
    const int* pool_dst = (const int*)d_in[11];
    const float* b_eps = (const float*)d_in[12];
    const float* b_W1 = (const float*)d_in[13];
    const float* b_b1 = (const float*)d_in[14];
    const float* b_g1 = (const float*)d_in[15];
    const float* b_be1 = (const float*)d_in[16];
    const float* b_W2 = (const float*)d_in[17];
    const float* b_b2 = (const float*)d_in[18];
    const float* o_eps = (const float*)d_in[19];
    const float* o_W1 = (const float*)d_in[20];
    const float* o_b1 = (const float*)d_in[21];
    const float* o_g1 = (const float*)d_in[22];
    const float* o_be1 = (const float*)d_in[23];
    const float* o_W2 = (const float*)d_in[24];
    const float* o_b2 = (const float*)d_in[25];
    const float* r_Wfc = (const float*)d_in[26];
    const float* r_al = (const float*)d_in[27];
    const float* r_ar = (const float*)d_in[28];
    const float* r_Wres = (const float*)d_in[29];
    const float* r_bias = (const float*)d_in[30];
    const float* r_g = (const float*)d_in[31];
    const float* r_b = (const float*)d_in[32];
    const float* r_Wout = (const float*)d_in[33];
    const float* r_bout = (const float*)d_in[34];
    const float* p_Wfc = (const float*)d_in[35];
    const float* p_al = (const float*)d_in[36];
    const float* p_ar = (const float*)d_in[37];
    const float* p_Wres = (const float*)d_in[38];
    const float* p_bias = (const float*)d_in[39];
    const float* p_g = (const float*)d_in[40];
    const float* p_b = (const float*)d_in[41];
    const float* p_Wout = (const float*)d_in[42];
    const float* p_bout = (const float*)d_in[43];

    float* out = (float*)d_out;
    char* wsb = (char*)d_ws;
    unsigned short* xAb = (unsigned short*)(wsb + 0);             // 25.6 MB
    unsigned short* xGb = (unsigned short*)(wsb + 26000000);      // 6.4 MB
    unsigned short* WtB1 = (unsigned short*)(wsb + 33000000);     // weight slots
    unsigned short* WtB2 = WtB1 + 32768;
    unsigned short* WtO1 = WtB2 + 32768;
    unsigned short* WtO2 = WtO1 + 32768;
    unsigned short* WtR  = WtO2 + 32768;   // 512x256 (Wfc|Wres)
    unsigned short* WtRo = WtR + 131072;   // 128x512
    unsigned short* WtP  = WtRo + 65536;   // 512x256
    unsigned short* WtPo = WtP + 131072;   // 128x512
    float* wv   = (float*)(wsb + 34100000);                       // 4x512 f32
    int* heads  = (int*)(wsb + 36300000);                         // 250k int
    int* nxt    = (int*)(wsb + 37400000);                         // 900k int
    unsigned short* h0A = (unsigned short*)(wsb + 41100000);      // 25.6 MB
    unsigned short* h0G = (unsigned short*)(wsb + 66800000);      // 6.4 MB
    unsigned short* R4a = (unsigned short*)(wsb + 73300000);      // 51.2 MB
    unsigned short* G1a = (unsigned short*)(wsb + 124600000);     // 25.6 MB
    unsigned short* G1g = (unsigned short*)(wsb + 150300000);     // 6.4 MB
    unsigned short* A2r = (unsigned short*)(wsb + 156800000);     // 102.4 MB
    unsigned short* A2p = (unsigned short*)(wsb + 259300000);     // 25.6 MB
    unsigned short* R3r = (unsigned short*)(wsb + 285000000);     // 102.4 MB
    unsigned short* R3p = (unsigned short*)(wsb + 387500000);     // 25.6 MB
    uint2* adj  = (uint2*)(wsb + 414000000);                      // 128 MB
    int* deg    = (int*)(wsb + 543000000);                        // 1 MB
    float* F    = (float*)(wsb + 544000000);                      // logit/ex block
    float* elR  = F;               // N_G*4
    float* elP  = F + 100000;      // N_A*4
    float* erR  = F + 500000;      // N_A*4
    float* erP  = F + 900000;      // N_G*4
    float* denR = F + 1000000;     // N_A*4
    float* denP = F + 1400000;     // N_G*4
    float* exR  = F + 1500000;     // E_R*4
    float* exP  = F + 2300000;     // E_P*4
    unsigned short* R4g = (unsigned short*)(wsb + 560000000);     // 12.8 MB

    // memsets for prep
    hipMemsetAsync(deg, 0, NSLOT * 4, stream);
    hipMemsetAsync(heads, 0xFF, NSLOT * 4, stream);
    hipMemsetAsync(denR, 0, 500000 * 4, stream);

    // 1. prep: xcast + wcast + war + adj_fill
    PrepArgs pa;
    pa.xa = x_atom; pa.xg = x_group; pa.xab = xAb; pa.xgb = xGb;
    pa.wc[0] = {b_W1, WtB1, 128, 256, 128, 0};
    pa.wc[1] = {b_W2, WtB2, 256, 128, 256, 0};
    pa.wc[2] = {o_W1, WtO1, 128, 256, 128, 0};
    pa.wc[3] = {o_W2, WtO2, 256, 128, 256, 0};
    pa.wc[4] = {r_Wfc, WtR, 128, 512, 256, 0};
    pa.wc[5] = {r_Wres, WtR, 128, 512, 256, 128};
    pa.wc[6] = {r_Wout, WtRo, 512, 128, 512, 0};
    pa.wc[7] = {p_Wfc, WtP, 128, 512, 256, 0};
    pa.wc[8] = {p_Wres, WtP, 128, 512, 256, 128};
    pa.wc[9] = {p_Wout, WtPo, 512, 128, 512, 0};
    pa.rWfc = r_Wfc; pa.ral = r_al; pa.rar = r_ar;
    pa.pWfc = p_Wfc; pa.pal = p_al; pa.par = p_ar; pa.wv = wv;
    pa.bs = bond_src; pa.bd = bond_dst; pa.os = ov_src; pa.od = ov_dst;
    pa.rs = ref_src; pa.rd = ref_dst; pa.ps = pool_src; pa.pd = pool_dst;
    pa.deg = deg; pa.adj = adj; pa.heads = heads; pa.nxt = nxt;
    k_prep<<<PB_XC + PB_WC + PB_WAR + 3516, 256, 0, stream>>>(pa);

    // 2. GINE gather + node logits
    k_gather_logit<<<31250 + 1954, 256, 0, stream>>>(
        xAb, xGb, ef_bond, ef_ov, bond_src, ov_src, deg, adj, heads, nxt,
        b_eps, o_eps, h0A, h0G, wv, elR, elP, erR, erP);

    // 3. edge exp + denominators
    k_exp_all<<<6250, 256, 0, stream>>>(elR, erR, elP, erP,
        ref_src, ref_dst, pool_src, pool_dst, exR, exP, denR, denP);

    // 4. GINE GEMM1 (both relations)
    k_gemm1<<<2 * NBA + 2 * NBG, 256, 0, stream>>>(h0A, h0G, WtB1, WtO1,
        b_b1, b_g1, b_be1, o_b1, o_g1, o_be1, R4a, R4g);

    // 5. GAT aggregation
    k_att_gather_all<<<31250, 256, 0, stream>>>(xAb, xGb, exR, exP, denR, denP, ref_src, pool_src,
                                                deg, adj, heads, nxt, A2r, A2p);

    // 6. GINE GEMM2 + GATK GEMMs
    k_gemm_mid<<<NBA + NBG + 4 * NBA + 4 * NBG, 256, 0, stream>>>(
        R4a, R4g, WtB2, WtO2, b_b2, o_b2, G1a, G1g,
        A2r, A2p, xAb, xGb, WtR, WtP,
        r_bias, r_g, r_b, p_bias, p_g, p_b, R3r, R3p);

    // 7. Wout GEMMs -> d_out
    k_gemm_out<<<NBA + NBG, 256, 0, stream>>>(R3r, R3p, WtRo, WtPo, r_bout, p_bout,
                                              G1a, G1g, out);
}